// Round 12
// baseline (14.802 us; speedup 1.0000x reference)
//
#include <hip/hip_runtime.h>
#include <cmath>

constexpr int Bn = 2, Hn = 256, Wn = 256, Cn = 2;
constexpr int NW = 4;    // waves per block; wave wv owns i in [64*wv, 64*wv+64)

__global__ __launch_bounds__(256, 8) void sinc_main_kernel(
    const float* __restrict__ img, const float* __restrict__ fmap,
    float* __restrict__ out)
{
    const float INV_PI = 0x1.45f306p-2f;  // float32(1/pi)

    __shared__ __align__(16) float sh_x[Cn][Hn];  // x0, [c][i] for quad reads
    __shared__ __align__(16) float sh_p[Cn][Hn];  // img * sin(pi*x0)/pi
    __shared__ float sh_acc[NW][64 * Cn];         // 2 KB partials (j-quarter)

    // grid = 2048: b = bid>>10, w = (bid>>2)&255, jq = bid&3.
    // Consecutive blocks share (b,w) -> same input slice, L2-friendly.
    const int bid = blockIdx.x;
    const int b   = bid >> 10;
    const int w   = (bid >> 2) & 255;
    const int jq  = bid & 3;
    const int t   = threadIdx.x;
    const int wv  = t >> 6;    // wave index
    const int l   = t & 63;

    // ---- Wave-local stage: wave wv stages i in [64wv, 64wv+64), both c. ----
    // 128 items, 64 lanes, 2 iterations. No block barrier needed before
    // compute: each wave reads only what it wrote itself.
#pragma unroll
    for (int k = 0; k < 2; ++k) {
        const int i = 64 * wv + 32 * k + (l >> 1), c = l & 1;
        const size_t off = (((size_t)b * Hn + i) * Wn + w) * Cn + c;
        const float f = fmap[off];
        float x0 = fminf(fmaxf(f + (float)i, 0.0f), 255.0f);
        const float n = rintf(x0);
        const float r = x0 - n;                              // [-0.5, 0.5]
        float sp = __builtin_amdgcn_sinf(0.5f * r) * INV_PI; // sin(pi*x0)/pi mag
        if (((int)n) & 1) sp = -sp;
        const float p = img[off] * sp;
        // Nudge: p==0 ⟺ row contributes nothing (x0 at integer / clip);
        // shift x0 so d = x0 - J is never exactly 0. Zero added error
        // (a p==0 row contributes 0 for ANY nonzero d).
        if (p == 0.0f) x0 += 0x1p-15f;
        sh_x[c][i] = x0;
        sh_p[c][i] = p;
    }
    // Same-wave LDS RAW fence: compute below reads only this wave's writes.
    __asm__ volatile("s_waitcnt lgkmcnt(0)" ::: "memory");

    // ---- Compute: lane l owns j = 64*jq + l; 16 quads (64 i's), 2 c. ----
    const float J = (float)(64 * jq + l);

    float acc0 = 0.0f, acc1 = 0.0f;

    const float4* qx = (const float4*)sh_x;   // index: c*64 + quad
    const float4* qp = (const float4*)sh_p;

#pragma unroll 1
    for (int qd = 0; qd < 16; ++qd) {         // 16 quads of 4 consecutive i's
        const int iq = wv * 16 + qd;
        const float4 x0q = qx[iq],      p0q = qp[iq];        // c = 0
        const float4 x1q = qx[64 + iq], p1q = qp[64 + iq];   // c = 1
        {   // channel 0: stable factored quad-merge, one rcp / 4 terms
            const float d0 = x0q.x - J, d1 = x0q.y - J;
            const float d2 = x0q.z - J, d3 = x0q.w - J;
            const float m01 = d0 * d1, m23 = d2 * d3;
            const float n01 = fmaf(p0q.x, d1, p0q.y * d0);
            const float n23 = fmaf(p0q.z, d3, p0q.w * d2);
            const float Nv  = fmaf(n01, m23, n23 * m01);
            acc0 = fmaf(Nv, __builtin_amdgcn_rcpf(m01 * m23), acc0);
        }
        {   // channel 1
            const float d0 = x1q.x - J, d1 = x1q.y - J;
            const float d2 = x1q.z - J, d3 = x1q.w - J;
            const float m01 = d0 * d1, m23 = d2 * d3;
            const float n01 = fmaf(p1q.x, d1, p1q.y * d0);
            const float n23 = fmaf(p1q.z, d3, p1q.w * d2);
            const float Nv  = fmaf(n01, m23, n23 * m01);
            acc1 = fmaf(Nv, __builtin_amdgcn_rcpf(m01 * m23), acc1);
        }
    }

    // ---- Partials -> LDS, reduce across the 4 waves. ----
    *(float2*)&sh_acc[wv][l * 2] = make_float2(acc0, acc1);
    __syncthreads();

    // ---- Final: thread t < 64 owns local j = t, stores float2 (both c). ----
    if (t < 64) {
        float a0 = 0.0f, a1 = 0.0f;
#pragma unroll
        for (int g = 0; g < NW; ++g) {
            const float2 v = *(const float2*)&sh_acc[g][t * 2];
            a0 += v.x; a1 += v.y;
        }
        const int j = 64 * jq + t;
        const float sgn = (j & 1) ? -1.0f : 1.0f;   // (-1)^j folded back in
        float2* o = (float2*)&out[(((size_t)b * Hn + j) * Wn + w) * Cn];
        *o = make_float2(sgn * a0, sgn * a1);
    }
}

extern "C" void kernel_launch(void* const* d_in, const int* in_sizes, int n_in,
                              void* d_out, int out_size, void* d_ws, size_t ws_size,
                              hipStream_t stream)
{
    (void)in_sizes; (void)n_in; (void)out_size; (void)d_ws; (void)ws_size;
    const float* img  = (const float*)d_in[0];
    const float* fmap = (const float*)d_in[1];
    float* out = (float*)d_out;
    sinc_main_kernel<<<Bn * Wn * 4, 256, 0, stream>>>(img, fmap, out);
}

// Round 13
// 13.189 us; speedup vs baseline: 1.1224x; 1.1224x over previous
//
#include <hip/hip_runtime.h>
#include <cmath>

constexpr int Bn = 2, Hn = 256, Wn = 256, Cn = 2;
constexpr int NG = 8;    // waves per block; wave wv owns i in [32*wv, 32*wv+32)
constexpr int NJ = 2;    // j's per thread: 128*jh + jl + {0, 64}

__global__ __launch_bounds__(512, 8) void sinc_main_kernel(
    const float* __restrict__ img, const float* __restrict__ fmap,
    float* __restrict__ out)
{
    const float INV_PI = 0x1.45f306p-2f;  // float32(1/pi)

    __shared__ __align__(16) float sh_x[Cn][Hn];  // x0, [c][i] for quad reads
    __shared__ __align__(16) float sh_p[Cn][Hn];  // img * sin(pi*x0)/pi
    __shared__ float sh_acc[NG][128 * Cn];        // 4 KB partials (j-half only)

    // grid = 1024: b = bid>>9, w = (bid>>1)&255, jh = bid&1.
    // Consecutive blocks share (b,w) -> same input slice, L2-friendly.
    const int bid = blockIdx.x;
    const int b   = bid >> 9;
    const int w   = (bid >> 1) & 255;
    const int jh  = bid & 1;
    const int t   = threadIdx.x;
    const int wv  = t >> 6;    // wave index
    const int l   = t & 63;

    // ---- Wave-local stage: all 64 lanes, lane owns (i = 32wv + l>>1, c = l&1).
    {
        const int i = 32 * wv + (l >> 1), c = l & 1;
        const size_t off = (((size_t)b * Hn + i) * Wn + w) * Cn + c;
        const float f = fmap[off];
        float x0 = fminf(fmaxf(f + (float)i, 0.0f), 255.0f);
        const float n = rintf(x0);
        const float r = x0 - n;                              // [-0.5, 0.5]
        float sp = __builtin_amdgcn_sinf(0.5f * r) * INV_PI; // sin(pi*x0)/pi mag
        if (((int)n) & 1) sp = -sp;
        const float p = img[off] * sp;
        // Nudge: p==0 ⟺ row contributes nothing (x0 at integer / clip);
        // shift x0 so d = x0 - J is never exactly 0. Zero added error.
        if (p == 0.0f) x0 += 0x1p-15f;
        sh_x[c][i] = x0;
        sh_p[c][i] = p;
    }
    // Same-wave LDS RAW fence: compute below reads only this wave's writes.
    __asm__ volatile("s_waitcnt lgkmcnt(0)" ::: "memory");

    // ---- Compute: thread (wv, l): 8 quads (32 i's), 2 j's, 2 channels. ----
    const int jl = l;

    float acc[NJ][2];
#pragma unroll
    for (int jj = 0; jj < NJ; ++jj) { acc[jj][0] = 0.0f; acc[jj][1] = 0.0f; }

    const float4* qx = (const float4*)sh_x;   // index: c*64 + quad
    const float4* qp = (const float4*)sh_p;

#pragma unroll 2
    for (int qd = 0; qd < 8; ++qd) {          // 8 quads of 4 consecutive i's
        const int iq = wv * 8 + qd;
        const float4 x0q = qx[iq],      p0q = qp[iq];        // c = 0
        const float4 x1q = qx[64 + iq], p1q = qp[64 + iq];   // c = 1
#pragma unroll
        for (int jj = 0; jj < NJ; ++jj) {
            const float J = (float)(128 * jh + jl + 64 * jj);
            {   // channel 0: stable factored quad-merge, one rcp / 4 terms
                const float d0 = x0q.x - J, d1 = x0q.y - J;
                const float d2 = x0q.z - J, d3 = x0q.w - J;
                const float m01 = d0 * d1, m23 = d2 * d3;
                const float n01 = fmaf(p0q.x, d1, p0q.y * d0);
                const float n23 = fmaf(p0q.z, d3, p0q.w * d2);
                const float Nv  = fmaf(n01, m23, n23 * m01);
                acc[jj][0] = fmaf(Nv, __builtin_amdgcn_rcpf(m01 * m23), acc[jj][0]);
            }
            {   // channel 1
                const float d0 = x1q.x - J, d1 = x1q.y - J;
                const float d2 = x1q.z - J, d3 = x1q.w - J;
                const float m01 = d0 * d1, m23 = d2 * d3;
                const float n01 = fmaf(p1q.x, d1, p1q.y * d0);
                const float n23 = fmaf(p1q.z, d3, p1q.w * d2);
                const float Nv  = fmaf(n01, m23, n23 * m01);
                acc[jj][1] = fmaf(Nv, __builtin_amdgcn_rcpf(m01 * m23), acc[jj][1]);
            }
        }
    }

    // ---- Partials -> LDS, reduce across the 8 i-groups. ----
#pragma unroll
    for (int jj = 0; jj < NJ; ++jj) {
        const int lj = jl + 64 * jj;          // local j in [0, 128)
        *(float2*)&sh_acc[wv][lj * 2] = make_float2(acc[jj][0], acc[jj][1]);
    }
    __syncthreads();

    // ---- Final: thread t < 128 owns local j = t, stores float2 (both c). ----
    if (t < 128) {
        float a0 = 0.0f, a1 = 0.0f;
#pragma unroll
        for (int g = 0; g < NG; ++g) {
            const float2 v = *(const float2*)&sh_acc[g][t * 2];
            a0 += v.x; a1 += v.y;
        }
        const int j = 128 * jh + t;
        const float sgn = (j & 1) ? -1.0f : 1.0f;   // (-1)^j folded back in
        float2* o = (float2*)&out[(((size_t)b * Hn + j) * Wn + w) * Cn];
        *o = make_float2(sgn * a0, sgn * a1);
    }
}

extern "C" void kernel_launch(void* const* d_in, const int* in_sizes, int n_in,
                              void* d_out, int out_size, void* d_ws, size_t ws_size,
                              hipStream_t stream)
{
    (void)in_sizes; (void)n_in; (void)out_size; (void)d_ws; (void)ws_size;
    const float* img  = (const float*)d_in[0];
    const float* fmap = (const float*)d_in[1];
    float* out = (float*)d_out;
    sinc_main_kernel<<<Bn * Wn * 2, 512, 0, stream>>>(img, fmap, out);
}